// Round 1
// baseline (1355.844 us; speedup 1.0000x reference)
//
#include <hip/hip_runtime.h>
#include <math.h>

// Problem constants
#define NB 4
#define NS 1024
#define ND 512
#define NE 8
#define NH 1536
#define NT 4096       // NB*NS
#define D6 3072

#define TS 64
#define BK 16

// 4x4 register-tile FMA
#define FMA16(acc, a, b) \
  acc[0][0] += a.x*b.x; acc[0][1] += a.x*b.y; acc[0][2] += a.x*b.z; acc[0][3] += a.x*b.w; \
  acc[1][0] += a.y*b.x; acc[1][1] += a.y*b.y; acc[1][2] += a.y*b.z; acc[1][3] += a.y*b.w; \
  acc[2][0] += a.z*b.x; acc[2][1] += a.z*b.y; acc[2][2] += a.z*b.z; acc[2][3] += a.z*b.w; \
  acc[3][0] += a.w*b.x; acc[3][1] += a.w*b.y; acc[3][2] += a.w*b.z; acc[3][3] += a.w*b.w;

// ---------------- K0: mods = silu(c) @ W_ada + b_ada  (B x 6D) ----------------
__global__ __launch_bounds__(256) void k_ada(const float* __restrict__ c,
    const float* __restrict__ Wada, const float* __restrict__ bada,
    float* __restrict__ mods)
{
  __shared__ float sc[ND];
  int tid = threadIdx.x;
  int idx = blockIdx.x * 256 + tid;      // 12288 total; 3072 % 256 == 0 -> one b per block
  int b = idx / D6;
  int j = idx - b * D6;
  for (int d = tid; d < ND; d += 256) {
    float v = c[b * ND + d];
    sc[d] = v / (1.f + expf(-v));
  }
  __syncthreads();
  float acc = bada[j];
  #pragma unroll 8
  for (int d = 0; d < ND; ++d)
    acc += sc[d] * Wada[(size_t)d * D6 + j];
  mods[b * D6 + j] = acc;
}

// ---------------- LN (+ optional modulate). X may alias Y (row-owned). -------
__global__ __launch_bounds__(256) void k_lnmod(const float* X, float* Y,
    const float* __restrict__ w, const float* __restrict__ b,
    const float* __restrict__ mods, int sh_off, int sc_off)
{
  __shared__ float red[16];
  int tid = threadIdx.x;
  int row = blockIdx.x;
  int batch = row >> 10;
  const float* xr = X + (size_t)row * ND;
  float x0 = xr[tid], x1 = xr[tid + 256];
  float s = x0 + x1, q = x0 * x0 + x1 * x1;
  #pragma unroll
  for (int off = 32; off > 0; off >>= 1) { s += __shfl_down(s, off, 64); q += __shfl_down(q, off, 64); }
  if ((tid & 63) == 0) { red[tid >> 6] = s; red[8 + (tid >> 6)] = q; }
  __syncthreads();
  if (tid == 0) {
    float S = red[0] + red[1] + red[2] + red[3];
    float Q = red[8] + red[9] + red[10] + red[11];
    float mean = S * (1.f / (float)ND);
    float var = Q * (1.f / (float)ND) - mean * mean;   // biased var, as torch LayerNorm
    red[0] = mean; red[1] = rsqrtf(var + 1e-5f);
  }
  __syncthreads();
  float mean = red[0], rstd = red[1];
  float* yr = Y + (size_t)row * ND;
  int d0 = tid, d1 = tid + 256;
  float y0 = (x0 - mean) * rstd * w[d0] + b[d0];
  float y1 = (x1 - mean) * rstd * w[d1] + b[d1];
  if (mods) {
    const float* mb = mods + batch * D6;
    y0 = y0 * (1.f + mb[sc_off + d0]) + mb[sh_off + d0];
    y1 = y1 * (1.f + mb[sc_off + d1]) + mb[sh_off + d1];
  }
  yr[d0] = y0; yr[d1] = y1;
}

// ---------------- generic NN GEMM: C = A(MxK) @ B(KxN), all dims %64/%16 -----
__global__ __launch_bounds__(256) void k_gemm_nn(const float* __restrict__ A,
    const float* __restrict__ Bm, float* __restrict__ C, int N, int K)
{
  __shared__ __align__(16) float As[BK][TS + 4];
  __shared__ __align__(16) float Bs[BK][TS + 4];
  int tid = threadIdx.x;
  int m0 = blockIdx.x * TS, n0 = blockIdx.y * TS;
  int tx = tid & 15, ty = tid >> 4;
  int am = tid >> 2, ak = (tid & 3) * 4;
  int bk = tid >> 4, bn = (tid & 15) * 4;
  float acc[4][4] = {};
  for (int k0 = 0; k0 < K; k0 += BK) {
    float4 av = *(const float4*)(A + (size_t)(m0 + am) * K + k0 + ak);
    float4 bv = *(const float4*)(Bm + (size_t)(k0 + bk) * N + n0 + bn);
    As[ak + 0][am] = av.x; As[ak + 1][am] = av.y; As[ak + 2][am] = av.z; As[ak + 3][am] = av.w;
    *(float4*)&Bs[bk][bn] = bv;
    __syncthreads();
    #pragma unroll
    for (int k = 0; k < BK; ++k) {
      float4 a = *(const float4*)&As[k][ty * 4];
      float4 b = *(const float4*)&Bs[k][tx * 4];
      FMA16(acc, a, b);
    }
    __syncthreads();
  }
  #pragma unroll
  for (int i = 0; i < 4; ++i) {
    float4 o = make_float4(acc[i][0], acc[i][1], acc[i][2], acc[i][3]);
    *(float4*)(C + (size_t)(m0 + ty * 4 + i) * N + n0 + tx * 4) = o;
  }
}

// ---------------- NN GEMM + residual epilogue: C = xres + g_msa*(A@B) --------
__global__ __launch_bounds__(256) void k_gemm_nn_resid(const float* __restrict__ A,
    const float* __restrict__ Bm, const float* __restrict__ xres,
    const float* __restrict__ mods, float* __restrict__ C)
{
  __shared__ __align__(16) float As[BK][TS + 4];
  __shared__ __align__(16) float Bs[BK][TS + 4];
  int tid = threadIdx.x;
  int m0 = blockIdx.x * TS, n0 = blockIdx.y * TS;
  int tx = tid & 15, ty = tid >> 4;
  int am = tid >> 2, ak = (tid & 3) * 4;
  int bk = tid >> 4, bn = (tid & 15) * 4;
  float acc[4][4] = {};
  for (int k0 = 0; k0 < ND; k0 += BK) {
    float4 av = *(const float4*)(A + (size_t)(m0 + am) * ND + k0 + ak);
    float4 bv = *(const float4*)(Bm + (size_t)(k0 + bk) * ND + n0 + bn);
    As[ak + 0][am] = av.x; As[ak + 1][am] = av.y; As[ak + 2][am] = av.z; As[ak + 3][am] = av.w;
    *(float4*)&Bs[bk][bn] = bv;
    __syncthreads();
    #pragma unroll
    for (int k = 0; k < BK; ++k) {
      float4 a = *(const float4*)&As[k][ty * 4];
      float4 b = *(const float4*)&Bs[k][tx * 4];
      FMA16(acc, a, b);
    }
    __syncthreads();
  }
  #pragma unroll
  for (int i = 0; i < 4; ++i) {
    int r = m0 + ty * 4 + i;
    int batch = r >> 10;
    const float* mb = mods + batch * D6 + 2 * ND + n0 + tx * 4;  // g_msa chunk
    float4 xv = *(const float4*)(xres + (size_t)r * ND + n0 + tx * 4);
    float4 o;
    o.x = xv.x + mb[0] * acc[i][0];
    o.y = xv.y + mb[1] * acc[i][1];
    o.z = xv.z + mb[2] * acc[i][2];
    o.w = xv.w + mb[3] * acc[i][3];
    *(float4*)(C + (size_t)r * ND + n0 + tx * 4) = o;
  }
}

// ------------- batched TN GEMM: scores[b,d,e] = sum_s q[b,s,d]*k[b,s,e] ------
__global__ __launch_bounds__(256) void k_gemm_tn(const float* __restrict__ Q,
    const float* __restrict__ Km, float* __restrict__ Sc)
{
  __shared__ __align__(16) float As[BK][TS + 4];
  __shared__ __align__(16) float Bs[BK][TS + 4];
  int z = blockIdx.z;
  const float* Qb = Q + (size_t)z * NS * ND;
  const float* Kb = Km + (size_t)z * NS * ND;
  float* Cb = Sc + (size_t)z * ND * ND;
  int tid = threadIdx.x;
  int m0 = blockIdx.x * TS, n0 = blockIdx.y * TS;
  int tx = tid & 15, ty = tid >> 4;
  int lm = tid & 63, lk = tid >> 6;   // 64 x 4 load mapping
  float acc[4][4] = {};
  for (int k0 = 0; k0 < NS; k0 += BK) {
    #pragma unroll
    for (int j = 0; j < 4; ++j) {
      int kk = lk + j * 4;
      As[kk][lm] = Qb[(size_t)(k0 + kk) * ND + m0 + lm];
      Bs[kk][lm] = Kb[(size_t)(k0 + kk) * ND + n0 + lm];
    }
    __syncthreads();
    #pragma unroll
    for (int k = 0; k < BK; ++k) {
      float4 a = *(const float4*)&As[k][ty * 4];
      float4 b = *(const float4*)&Bs[k][tx * 4];
      FMA16(acc, a, b);
    }
    __syncthreads();
  }
  #pragma unroll
  for (int i = 0; i < 4; ++i) {
    float4 o = make_float4(acc[i][0], acc[i][1], acc[i][2], acc[i][3]);
    *(float4*)(Cb + (size_t)(m0 + ty * 4 + i) * ND + n0 + tx * 4) = o;
  }
}

// --------- softmax over rows of 512 (in place), rows = B*D -------------------
__global__ __launch_bounds__(256) void k_softmax512(float* Sc)
{
  __shared__ float red[16];
  int tid = threadIdx.x;
  float* r = Sc + (size_t)blockIdx.x * ND;
  float x0 = r[tid], x1 = r[tid + 256];
  float m = fmaxf(x0, x1);
  #pragma unroll
  for (int off = 32; off > 0; off >>= 1) m = fmaxf(m, __shfl_down(m, off, 64));
  if ((tid & 63) == 0) red[tid >> 6] = m;
  __syncthreads();
  if (tid == 0) red[0] = fmaxf(fmaxf(red[0], red[1]), fmaxf(red[2], red[3]));
  __syncthreads();
  m = red[0];
  float e0 = expf(x0 - m), e1 = expf(x1 - m);
  float s = e0 + e1;
  #pragma unroll
  for (int off = 32; off > 0; off >>= 1) s += __shfl_down(s, off, 64);
  if ((tid & 63) == 0) red[8 + (tid >> 6)] = s;
  __syncthreads();
  if (tid == 0) red[8] = red[8] + red[9] + red[10] + red[11];
  __syncthreads();
  float inv = 1.f / red[8];
  r[tid] = e0 * inv; r[tid + 256] = e1 * inv;
}

// -------- batched NT GEMM: attn0[b,s,d] = sum_e V[b,s,e]*A[b,d,e] ------------
__global__ __launch_bounds__(256) void k_gemm_nt(const float* __restrict__ V,
    const float* __restrict__ Am, float* __restrict__ O)
{
  __shared__ __align__(16) float As[BK][TS + 4];
  __shared__ __align__(16) float Bs[BK][TS + 4];
  int z = blockIdx.z;
  const float* Vb = V + (size_t)z * NS * ND;
  const float* Ab = Am + (size_t)z * ND * ND;
  float* Ob = O + (size_t)z * NS * ND;
  int tid = threadIdx.x;
  int m0 = blockIdx.x * TS, n0 = blockIdx.y * TS;
  int tx = tid & 15, ty = tid >> 4;
  int am = tid >> 2, ak = (tid & 3) * 4;
  float acc[4][4] = {};
  for (int k0 = 0; k0 < ND; k0 += BK) {
    float4 av = *(const float4*)(Vb + (size_t)(m0 + am) * ND + k0 + ak);
    float4 bv = *(const float4*)(Ab + (size_t)(n0 + am) * ND + k0 + ak); // B[k][n]=Am[n,k]
    As[ak + 0][am] = av.x; As[ak + 1][am] = av.y; As[ak + 2][am] = av.z; As[ak + 3][am] = av.w;
    Bs[ak + 0][am] = bv.x; Bs[ak + 1][am] = bv.y; Bs[ak + 2][am] = bv.z; Bs[ak + 3][am] = bv.w;
    __syncthreads();
    #pragma unroll
    for (int k = 0; k < BK; ++k) {
      float4 a = *(const float4*)&As[k][ty * 4];
      float4 b = *(const float4*)&Bs[k][tx * 4];
      FMA16(acc, a, b);
    }
    __syncthreads();
  }
  #pragma unroll
  for (int i = 0; i < 4; ++i) {
    float4 o = make_float4(acc[i][0], acc[i][1], acc[i][2], acc[i][3]);
    *(float4*)(Ob + (size_t)(m0 + ty * 4 + i) * ND + n0 + tx * 4) = o;
  }
}

// -------- router logits = xm @ Wr + br  (T x 8) ------------------------------
__global__ __launch_bounds__(256) void k_router(const float* __restrict__ xm,
    const float* __restrict__ Wr, const float* __restrict__ br, float* __restrict__ logits)
{
  int idx = blockIdx.x * 256 + threadIdx.x;   // 32768
  int t = idx >> 3, e = idx & 7;
  float acc = br[e];
  const float* xr = xm + (size_t)t * ND;
  #pragma unroll 4
  for (int d = 0; d < ND; ++d) acc += xr[d] * Wr[d * NE + e];
  logits[idx] = acc;
}

// -------- nrm[b,e] = sqrt(sum_s logits^2) (F.normalize over seq axis) --------
__global__ __launch_bounds__(256) void k_colnorm(const float* __restrict__ logits,
    float* __restrict__ nrm)
{
  __shared__ float red[8];
  int tid = threadIdx.x;
  int b = blockIdx.x >> 3, e = blockIdx.x & 7;
  float acc = 0.f;
  for (int s = tid; s < NS; s += 256) {
    float l = logits[((size_t)(b << 10) + s) * NE + e];
    acc += l * l;
  }
  #pragma unroll
  for (int off = 32; off > 0; off >>= 1) acc += __shfl_down(acc, off, 64);
  if ((tid & 63) == 0) red[tid >> 6] = acc;
  __syncthreads();
  if (tid == 0) nrm[b * NE + e] = sqrtf(red[0] + red[1] + red[2] + red[3]);
}

__global__ void k_zero16(int* p) { if (threadIdx.x < 16) p[threadIdx.x] = 0; }

// -------- per-token: probs, top-2, expert counts -----------------------------
__global__ __launch_bounds__(256) void k_top2(const float* __restrict__ logits,
    const float* __restrict__ nrm, float* __restrict__ probs,
    float* __restrict__ wsel, int* __restrict__ isel, int* __restrict__ cnt)
{
  int t = blockIdx.x * 256 + threadIdx.x;  // 4096
  int b = t >> 10;
  float p[NE];
  float mx = -1e30f;
  #pragma unroll
  for (int e = 0; e < NE; ++e) {
    float l = logits[t * NE + e] / fmaxf(nrm[b * NE + e], 1e-12f);
    p[e] = l;
    mx = fmaxf(mx, l);
  }
  float s = 0.f;
  #pragma unroll
  for (int e = 0; e < NE; ++e) { p[e] = expf(p[e] - mx); s += p[e]; }
  float inv = 1.f / s;
  #pragma unroll
  for (int e = 0; e < NE; ++e) { p[e] *= inv; probs[t * NE + e] = p[e]; }
  int i1 = 0;
  #pragma unroll
  for (int e = 1; e < NE; ++e) if (p[e] > p[i1]) i1 = e;   // ties -> lowest idx, as lax.top_k
  int i2 = (i1 == 0) ? 1 : 0;
  #pragma unroll
  for (int e = 0; e < NE; ++e) if (e != i1 && p[e] > p[i2]) i2 = e;
  wsel[t * 2] = p[i1]; wsel[t * 2 + 1] = p[i2];
  isel[t * 2] = i1;    isel[t * 2 + 1] = i2;
  atomicAdd(&cnt[i1], 1); atomicAdd(&cnt[i2], 1);
}

__global__ void k_scan(const int* __restrict__ cnt, int* __restrict__ offs)
{
  if (threadIdx.x == 0) {
    int a = 0;
    for (int e = 0; e < NE; ++e) { offs[e] = a; a += cnt[e]; }
    offs[NE] = a;
  }
}

__global__ __launch_bounds__(256) void k_fill(const int* __restrict__ isel,
    const float* __restrict__ wsel, const int* __restrict__ offs,
    int* __restrict__ cnt2, int* __restrict__ list, float* __restrict__ lw)
{
  int idx = blockIdx.x * 256 + threadIdx.x;  // 8192
  int e = isel[idx];
  int pos = atomicAdd(&cnt2[e], 1);
  int slot = offs[e] + pos;
  list[slot] = idx >> 1;
  lw[slot] = wsel[idx];
}

// -------- aux = sum_{s,e} (1/E - mean_b probs)^2 -----------------------------
__global__ __launch_bounds__(256) void k_aux(const float* __restrict__ probs,
    float* __restrict__ outAux)
{
  __shared__ float red[8];
  int tid = threadIdx.x;
  float acc = 0.f;
  for (int s = tid; s < NS; s += 256) {
    #pragma unroll
    for (int e = 0; e < NE; ++e) {
      float a = probs[(size_t)s * NE + e] + probs[(size_t)(NS + s) * NE + e]
              + probs[(size_t)(2 * NS + s) * NE + e] + probs[(size_t)(3 * NS + s) * NE + e];
      float d = 0.125f - a * 0.25f;
      acc += d * d;
    }
  }
  #pragma unroll
  for (int off = 32; off > 0; off >>= 1) acc += __shfl_down(acc, off, 64);
  if ((tid & 63) == 0) red[tid >> 6] = acc;
  __syncthreads();
  if (tid == 0) *outAux = red[0] + red[1] + red[2] + red[3];
}

// -------- MoE stage 1: gate[slot,h] = sin(xm@W1_e)*(xm@W3_e) -----------------
__global__ __launch_bounds__(256) void k_moe1(const float* __restrict__ xm,
    const float* __restrict__ W1, const float* __restrict__ W3,
    const int* __restrict__ list, const int* __restrict__ offs,
    float* __restrict__ gate)
{
  int e = blockIdx.z;
  int base = offs[e], ne = offs[e + 1] - base;
  int m0 = blockIdx.x * TS;
  if (m0 >= ne) return;
  int n0 = blockIdx.y * TS;
  const float* B1 = W1 + (size_t)e * ND * NH;
  const float* B3 = W3 + (size_t)e * ND * NH;
  __shared__ __align__(16) float As[BK][TS + 4];
  __shared__ __align__(16) float Bs1[BK][TS + 4];
  __shared__ __align__(16) float Bs3[BK][TS + 4];
  __shared__ int rowt[TS];
  int tid = threadIdx.x;
  if (tid < TS) {
    int r = m0 + tid;
    rowt[tid] = (r < ne) ? list[base + r] : -1;
  }
  __syncthreads();
  int tx = tid & 15, ty = tid >> 4;
  int am = tid >> 2, ak = (tid & 3) * 4;
  int bk = tid >> 4, bn = (tid & 15) * 4;
  int t = rowt[am];
  float acc1[4][4] = {}, acc3[4][4] = {};
  for (int k0 = 0; k0 < ND; k0 += BK) {
    float4 av = make_float4(0.f, 0.f, 0.f, 0.f);
    if (t >= 0) av = *(const float4*)(xm + (size_t)t * ND + k0 + ak);
    float4 b1 = *(const float4*)(B1 + (size_t)(k0 + bk) * NH + n0 + bn);
    float4 b3 = *(const float4*)(B3 + (size_t)(k0 + bk) * NH + n0 + bn);
    As[ak + 0][am] = av.x; As[ak + 1][am] = av.y; As[ak + 2][am] = av.z; As[ak + 3][am] = av.w;
    *(float4*)&Bs1[bk][bn] = b1;
    *(float4*)&Bs3[bk][bn] = b3;
    __syncthreads();
    #pragma unroll
    for (int k = 0; k < BK; ++k) {
      float4 a = *(const float4*)&As[k][ty * 4];
      float4 b = *(const float4*)&Bs1[k][tx * 4];
      float4 d = *(const float4*)&Bs3[k][tx * 4];
      FMA16(acc1, a, b);
      FMA16(acc3, a, d);
    }
    __syncthreads();
  }
  #pragma unroll
  for (int i = 0; i < 4; ++i) {
    int r = m0 + ty * 4 + i;
    if (r < ne) {
      float4 o;
      o.x = sinf(acc1[i][0]) * acc3[i][0];
      o.y = sinf(acc1[i][1]) * acc3[i][1];
      o.z = sinf(acc1[i][2]) * acc3[i][2];
      o.w = sinf(acc1[i][3]) * acc3[i][3];
      *(float4*)(gate + (size_t)(base + r) * NH + n0 + tx * 4) = o;
    }
  }
}

// -------- MoE stage 2: out[t,:] += w * (gate[slot,:] @ W2_e) -----------------
__global__ __launch_bounds__(256) void k_moe2(const float* __restrict__ gate,
    const float* __restrict__ W2, const int* __restrict__ list,
    const int* __restrict__ offs, const float* __restrict__ lw,
    float* __restrict__ outp)
{
  int e = blockIdx.z;
  int base = offs[e], ne = offs[e + 1] - base;
  int m0 = blockIdx.x * TS;
  if (m0 >= ne) return;
  int n0 = blockIdx.y * TS;
  const float* B2 = W2 + (size_t)e * NH * ND;
  __shared__ __align__(16) float As[BK][TS + 4];
  __shared__ __align__(16) float Bs[BK][TS + 4];
  int tid = threadIdx.x;
  int tx = tid & 15, ty = tid >> 4;
  int am = tid >> 2, ak = (tid & 3) * 4;
  int bk = tid >> 4, bn = (tid & 15) * 4;
  bool mvalid = (m0 + am) < ne;
  float acc[4][4] = {};
  for (int k0 = 0; k0 < NH; k0 += BK) {
    float4 av = make_float4(0.f, 0.f, 0.f, 0.f);
    if (mvalid) av = *(const float4*)(gate + (size_t)(base + m0 + am) * NH + k0 + ak);
    float4 bv = *(const float4*)(B2 + (size_t)(k0 + bk) * ND + n0 + bn);
    As[ak + 0][am] = av.x; As[ak + 1][am] = av.y; As[ak + 2][am] = av.z; As[ak + 3][am] = av.w;
    *(float4*)&Bs[bk][bn] = bv;
    __syncthreads();
    #pragma unroll
    for (int k = 0; k < BK; ++k) {
      float4 a = *(const float4*)&As[k][ty * 4];
      float4 b = *(const float4*)&Bs[k][tx * 4];
      FMA16(acc, a, b);
    }
    __syncthreads();
  }
  #pragma unroll
  for (int i = 0; i < 4; ++i) {
    int r = m0 + ty * 4 + i;
    if (r < ne) {
      int t = list[base + r];
      float w = lw[base + r];
      #pragma unroll
      for (int j = 0; j < 4; ++j)
        atomicAdd(outp + (size_t)t * ND + n0 + tx * 4 + j, w * acc[i][j]);
    }
  }
}

// ---------------- workspace layout (float offsets); needs ws >= 64 MB --------
static const size_t OFF_MODS = 0;           // 12288
static const size_t OFF_H    = 16384;       // 2097152
static const size_t OFF_QP   = 2113536;     // 2097152
static const size_t OFF_KP   = 4210688;     // 2097152
static const size_t OFF_VV   = 6307840;     // 2097152
static const size_t OFF_SC   = 8404992;     // 1048576
static const size_t OFF_AT0  = 9453568;     // 2097152
static const size_t OFF_X2   = 11550720;    // 2097152
static const size_t OFF_XM   = 13647872;    // 2097152
static const size_t OFF_LOGI = 15745024;    // 32768
static const size_t OFF_NRM  = 15777792;    // 32
static const size_t OFF_PROB = 15777824;    // 32768
static const size_t OFF_WSEL = 15810592;    // 8192
static const size_t OFF_LWS  = 15818784;    // 8192
static const size_t OFF_INTS = 15826976;    // 16416 ints
static const size_t OFF_GATE = 16384;       // 12582912 floats; aliases H..X2 (dead by MoE)

extern "C" void kernel_launch(void* const* d_in, const int* in_sizes, int n_in,
                              void* d_out, int out_size, void* d_ws, size_t ws_size,
                              hipStream_t stream)
{
  const float* x    = (const float*)d_in[0];
  const float* c    = (const float*)d_in[1];
  const float* Wada = (const float*)d_in[2];
  const float* bada = (const float*)d_in[3];
  const float* Wq   = (const float*)d_in[4];
  const float* Wk   = (const float*)d_in[5];
  const float* Wv   = (const float*)d_in[6];
  const float* Wo   = (const float*)d_in[7];
  const float* qn_w = (const float*)d_in[8];
  const float* qn_b = (const float*)d_in[9];
  const float* kn_w = (const float*)d_in[10];
  const float* kn_b = (const float*)d_in[11];
  const float* an_w = (const float*)d_in[12];
  const float* an_b = (const float*)d_in[13];
  const float* fn_w = (const float*)d_in[14];
  const float* fn_b = (const float*)d_in[15];
  const float* Wr   = (const float*)d_in[16];
  const float* br   = (const float*)d_in[17];
  const float* W1   = (const float*)d_in[18];
  const float* W2   = (const float*)d_in[19];
  const float* W3   = (const float*)d_in[20];
  float* out = (float*)d_out;
  float* ws  = (float*)d_ws;
  int* ib   = (int*)(ws + OFF_INTS);
  int* isel = ib;
  int* cnt  = ib + 8192;
  int* cnt2 = ib + 8200;
  int* offs = ib + 8208;
  int* list = ib + 8224;

  // zero moe accumulator region of the output (aux written directly by k_aux)
  hipMemsetAsync(out, 0, (size_t)NT * ND * sizeof(float), stream);

  k_ada<<<48, 256, 0, stream>>>(c, Wada, bada, ws + OFF_MODS);
  k_lnmod<<<NT, 256, 0, stream>>>(x, ws + OFF_H, an_w, an_b, ws + OFF_MODS, 0, 512);
  k_gemm_nn<<<dim3(64, 8), 256, 0, stream>>>(ws + OFF_H, Wq, ws + OFF_QP, 512, 512);
  k_gemm_nn<<<dim3(64, 8), 256, 0, stream>>>(ws + OFF_H, Wk, ws + OFF_KP, 512, 512);
  k_gemm_nn<<<dim3(64, 8), 256, 0, stream>>>(ws + OFF_H, Wv, ws + OFF_VV, 512, 512);
  k_lnmod<<<NT, 256, 0, stream>>>(ws + OFF_QP, ws + OFF_QP, qn_w, qn_b, nullptr, 0, 0);
  k_lnmod<<<NT, 256, 0, stream>>>(ws + OFF_KP, ws + OFF_KP, kn_w, kn_b, nullptr, 0, 0);
  k_gemm_tn<<<dim3(8, 8, 4), 256, 0, stream>>>(ws + OFF_QP, ws + OFF_KP, ws + OFF_SC);
  k_softmax512<<<2048, 256, 0, stream>>>(ws + OFF_SC);
  k_gemm_nt<<<dim3(16, 8, 4), 256, 0, stream>>>(ws + OFF_VV, ws + OFF_SC, ws + OFF_AT0);
  k_gemm_nn_resid<<<dim3(64, 8), 256, 0, stream>>>(ws + OFF_AT0, Wo, x, ws + OFF_MODS, ws + OFF_X2);
  k_lnmod<<<NT, 256, 0, stream>>>(ws + OFF_X2, ws + OFF_XM, fn_w, fn_b, ws + OFF_MODS, 1536, 2048);
  k_router<<<128, 256, 0, stream>>>(ws + OFF_XM, Wr, br, ws + OFF_LOGI);
  k_zero16<<<1, 64, 0, stream>>>(cnt);
  k_colnorm<<<32, 256, 0, stream>>>(ws + OFF_LOGI, ws + OFF_NRM);
  k_top2<<<16, 256, 0, stream>>>(ws + OFF_LOGI, ws + OFF_NRM, ws + OFF_PROB,
                                 ws + OFF_WSEL, isel, cnt);
  k_scan<<<1, 64, 0, stream>>>(cnt, offs);
  k_fill<<<32, 256, 0, stream>>>(isel, ws + OFF_WSEL, offs, cnt2, list, ws + OFF_LWS);
  k_aux<<<1, 256, 0, stream>>>(ws + OFF_PROB, out + (size_t)NT * ND);
  k_moe1<<<dim3(64, 24, 8), 256, 0, stream>>>(ws + OFF_XM, W1, W3, list, offs, ws + OFF_GATE);
  k_moe2<<<dim3(64, 8, 8), 256, 0, stream>>>(ws + OFF_GATE, W2, list, offs, ws + OFF_LWS, out);
}